// Round 9
// baseline (861.662 us; speedup 1.0000x reference)
//
#include <hip/hip_runtime.h>
#include <hip/hip_bf16.h>

// GraphRNN, fp32 I/O (reference dtypes are float32).
// beta = (seq @ E) / rowsum(graph); agg = graph^T @ beta (per batch);
// Xpre = agg @ Wx + b; then 1024-step scan h = tanh(Xpre_m + h @ Wh).
// MFMA path: fp32 operands split into bf16 hi+lo (rel err ~2^-18).
//
// R20: producer-consumer fusion. Scan math frozen (R15, 622us; R16/R17
// edits regressed). Front time (~150us) has been invariant under launch
// merging and work dedup -> attack it by OVERLAP: agg+xpre for one
// (b, mtile-of-64) is self-contained (agg rows then xpre on them), so a
// single fused kernel runs 128 producer blocks + 8 scan blocks (136 <=
// 256 CUs -> all co-resident; producers wait on nothing -> no deadlock).
// Producers signal xpref[mtile] (8 b-signals each) with threadfence +
// release atomic; scan spin-waits (acquire, agent scope) at prologue and
// at 64-row Xpre boundaries. Prefetch distance 4 steps (~5800cy) means
// post-handoff spins never fire. Producer/scan arithmetic is R19/R15
// verbatim per element -> absmax unchanged.

typedef unsigned short u16;
typedef unsigned int u32;
typedef __bf16 bf16_t;
typedef __bf16 bf16x8 __attribute__((ext_vector_type(8)));
typedef float f32x4 __attribute__((ext_vector_type(4)));
typedef unsigned short u16x8 __attribute__((ext_vector_type(8)));
typedef unsigned short u16x4 __attribute__((ext_vector_type(4)));

#define LDS_P 72   // LDS pitch (u16) for staged tiles
#define HP_B  288  // h LDS row pitch (u16) in the scan

struct HiLo { u16 hi, lo; };

__device__ __forceinline__ u16 f2bf(float f) {
  bf16_t h = (bf16_t)f;  // RNE
  return __builtin_bit_cast(u16, h);
}
__device__ __forceinline__ HiLo splitf(float v) {
  bf16_t h = (bf16_t)v;
  HiLo r;
  r.hi = __builtin_bit_cast(u16, h);
  r.lo = f2bf(v - (float)h);
  return r;
}
__device__ __forceinline__ float tanh_fast(float x) {
  float ax = fabsf(x);
  float e  = __expf(-2.0f * ax);
  float t  = __fdividef(1.0f - e, 1.0f + e);
  return copysignf(t, x);
}
// Barrier with LDS-only visibility (drains lgkmcnt, not vmcnt).
__device__ __forceinline__ void sync_lds_only() {
  __asm__ volatile("s_waitcnt lgkmcnt(0)\ns_barrier" ::: "memory");
}
// Spin until xpref[tl] == 8 (all 8 batches' producers signaled tile tl).
__device__ __forceinline__ void wait_tile(volatile unsigned int* xpref, int tl) {
  while (__hip_atomic_load(&xpref[tl], __ATOMIC_ACQUIRE,
                           __HIP_MEMORY_SCOPE_AGENT) < 8u) {
    __builtin_amdgcn_s_sleep(4);
  }
  __threadfence();  // belt-and-suspenders invalidate before data reads
}

// ---------------- K1 front1 (512 thr): beta + weight splits + rowsums -------
// bid <  256 : raw betaT 64x128 stripe.
// 256..511   : transpose+split Wx/Wh, 2 columns per block (bid 256 also
//              zeroes the xpref flags for this launch iteration).
// 512..1535  : rnorm rows (bid-512)*8 .. +8 (one row per wave).
__global__ __launch_bounds__(512, 2) void front1(
    const float* __restrict__ Wx, u16* __restrict__ Wxth, u16* __restrict__ Wxtl,
    const float* __restrict__ Wh, u16* __restrict__ Whth, u16* __restrict__ Whtl,
    const float* __restrict__ graph, float* __restrict__ rnorm,
    const float* __restrict__ seq, const float* __restrict__ E,
    u16* __restrict__ betaTh, u16* __restrict__ betaTl,
    unsigned int* __restrict__ xpref) {
  __shared__ u16 Ah[64 * LDS_P], Al[64 * LDS_P];
  __shared__ u16 Bh[128 * LDS_P], Bl[128 * LDS_P];
  const int bid = blockIdx.x;
  const int t = threadIdx.x;

  if (bid >= 256 && bid < 512) {  // weight transpose+split, 2 cols/block
    if (bid == 256 && t < 16) xpref[t] = 0;   // reset flags (stream-ordered)
    const int wbid = bid - 256;
    const int u = ((wbid & 127) << 1) + (t >> 8), d = t & 255;
    const float* s; u16 *dh, *dl;
    if (wbid < 128) { s = Wx; dh = Wxth; dl = Wxtl; }
    else            { s = Wh; dh = Whth; dl = Whtl; }
    HiLo r = splitf(s[d * 256 + u]);
    dh[u * 256 + d] = r.hi;
    dl[u * 256 + d] = r.lo;
    return;
  }
  if (bid >= 512) {  // graph row-sums, 8 rows/block
    const int wave = t >> 6, lane = t & 63;
    const int row = (bid - 512) * 8 + wave;  // 0..8191
    const float* p = graph + (size_t)row * 1024 + lane * 16;
    float s = 0.f;
#pragma unroll
    for (int c = 0; c < 4; c++) {
      f32x4 v = *(const f32x4*)(p + c * 4);
#pragma unroll
      for (int j = 0; j < 4; j++) s += v[j];
    }
#pragma unroll
    for (int off = 32; off > 0; off >>= 1) s += __shfl_xor(s, off);
    if (lane == 0) rnorm[row] = 1.0f / fmaxf(s, 1e-7f);
    return;
  }

  // ---- raw beta (seq @ E): 64 rows x 128 u per block ----
  const int v = bid;                          // 0..255
  const int w = t >> 6, lane = t & 63, quad = lane >> 4, l16 = lane & 15;
  const int msub = w & 3, nsub = w >> 2;
  const int r0 = (v >> 1) * 64, n_base = (v & 1) * 128;
  f32x4 acc[4];
#pragma unroll
  for (int i = 0; i < 4; i++) acc[i] = (f32x4){0.f, 0.f, 0.f, 0.f};

  for (int kb = 0; kb < 256; kb += 64) {
#pragma unroll
    for (int cc = 0; cc < 2; cc++) {  // A: seq 64 rows x 64 k, split hi/lo
      int c = t + cc * 512;
      int r = c >> 4, c4 = c & 15;
      f32x4 vv = *(const f32x4*)(seq + (size_t)(r0 + r) * 256 + kb + c4 * 4);
      u16x4 hi, lo;
#pragma unroll
      for (int j = 0; j < 4; j++) {
        HiLo s = splitf(vv[j]);
        hi[j] = s.hi; lo[j] = s.lo;
      }
      *(u16x4*)(Ah + r * LDS_P + c4 * 4) = hi;
      *(u16x4*)(Al + r * LDS_P + c4 * 4) = lo;
    }
#pragma unroll
    for (int cc = 0; cc < 4; cc++) {  // B: E[d][u] 64 d x 128 u, transposed
      int c = t + cc * 512;
      int r = c >> 5, c5 = c & 31;    // r = d_local, c5 = u-chunk of 4
      f32x4 vv = *(const f32x4*)(E + (size_t)(kb + r) * 256 + n_base + c5 * 4);
#pragma unroll
      for (int j = 0; j < 4; j++) {
        HiLo s = splitf(vv[j]);
        Bh[(c5 * 4 + j) * LDS_P + r] = s.hi;
        Bl[(c5 * 4 + j) * LDS_P + r] = s.lo;
      }
    }
    __syncthreads();
#pragma unroll
    for (int kk = 0; kk < 64; kk += 32) {
      bf16x8 ah = __builtin_bit_cast(bf16x8, *(const u16x8*)(Ah + (msub * 16 + l16) * LDS_P + kk + quad * 8));
      bf16x8 al = __builtin_bit_cast(bf16x8, *(const u16x8*)(Al + (msub * 16 + l16) * LDS_P + kk + quad * 8));
#pragma unroll
      for (int tN = 0; tN < 4; tN++) {
        int brow = nsub * 64 + tN * 16 + l16;
        bf16x8 bh = __builtin_bit_cast(bf16x8, *(const u16x8*)(Bh + brow * LDS_P + kk + quad * 8));
        bf16x8 bl = __builtin_bit_cast(bf16x8, *(const u16x8*)(Bl + brow * LDS_P + kk + quad * 8));
        acc[tN] = __builtin_amdgcn_mfma_f32_16x16x32_bf16(ah, bh, acc[tN], 0, 0, 0);
        acc[tN] = __builtin_amdgcn_mfma_f32_16x16x32_bf16(ah, bl, acc[tN], 0, 0, 0);
        acc[tN] = __builtin_amdgcn_mfma_f32_16x16x32_bf16(al, bh, acc[tN], 0, 0, 0);
      }
    }
    __syncthreads();
  }
  const int rbase = r0 + msub * 16 + quad * 4;  // b*1024 + l
  const int bI = rbase >> 10, lI = rbase & 1023;
#pragma unroll
  for (int tN = 0; tN < 4; tN++) {
    int u = n_base + nsub * 64 + tN * 16 + l16;
    u16x4 hv, lv;
#pragma unroll
    for (int i = 0; i < 4; i++) {
      HiLo s = splitf(acc[tN][i]);   // raw beta (rnorm folded into agg)
      hv[i] = s.hi; lv[i] = s.lo;
    }
    size_t off = ((size_t)bI << 18) + (size_t)u * 1024 + lI;
    *(u16x4*)(betaTh + off) = hv;
    *(u16x4*)(betaTl + off) = lv;
  }
}

// ---------------- K2 back_fused: 128 producer blocks + 8 scan blocks --------
// Producer pid = mtile*8 + b (pid < 128): agg rows (b, m0..m0+63) x 256 u
// (two R19-agg halves), then xpre on those rows (two R19-xpre halves),
// then threadfence + release-signal xpref[mtile]. Scan blocks (pid >=
// 128, b = pid-128): R15 scan + acquire spin-waits on xpref at prologue
// and at 64-row Xpre boundaries.
__global__ __launch_bounds__(512, 2) void back_fused(
    const float* __restrict__ graph,
    const u16* __restrict__ betaTh, const u16* __restrict__ betaTl,
    const float* __restrict__ rnorm, float* __restrict__ agg,
    const u16* __restrict__ Wxth, const u16* __restrict__ Wxtl,
    const float* __restrict__ bias, float* __restrict__ Xpre,
    const u16* __restrict__ Whth, const u16* __restrict__ Whtl,
    float* __restrict__ out, unsigned int* __restrict__ xpref) {
  __shared__ u16 Ah[64 * LDS_P], Al[64 * LDS_P];
  __shared__ u16 Bh[128 * LDS_P], Bl[128 * LDS_P];
  __shared__ u16 h2[2][2 * HP_B];
  const int pid = blockIdx.x;
  const int t = threadIdx.x;

  if (pid < 128) {
    // =================== producer: agg then xpre =======================
    const int mtile = pid >> 3, b = pid & 7;
    const int m0 = mtile * 64;
    const int w = t >> 6, lane = t & 63, quad = lane >> 4, l16 = lane & 15;
    const int msub = w & 3, nsub = w >> 2;
    const float* g = graph + (size_t)b * (1024 * 1024);
    const float* rnb = rnorm + b * 1024;
    const size_t bt = (size_t)b << 18;

    // ---- agg phase: two 64m x 128u halves ----
    for (int half = 0; half < 2; ++half) {
      const int n_base = half * 128;
      f32x4 acc[4];
#pragma unroll
      for (int i = 0; i < 4; i++) acc[i] = (f32x4){0.f, 0.f, 0.f, 0.f};

      for (int kb = 0; kb < 1024; kb += 64) {
#pragma unroll
        for (int cc = 0; cc < 2; cc++) {  // A: graph 64l x 64m, transp + rn
          int c = t + cc * 512;
          int r = c >> 4, c4 = c & 15;
          f32x4 vv = *(const f32x4*)(g + (size_t)(kb + r) * 1024 + m0 + c4 * 4);
          float rn = rnb[kb + r];
#pragma unroll
          for (int j = 0; j < 4; j++) {
            HiLo s = splitf(vv[j] * rn);
            Ah[(c4 * 4 + j) * LDS_P + r] = s.hi;
            Al[(c4 * 4 + j) * LDS_P + r] = s.lo;
          }
        }
#pragma unroll
        for (int cc = 0; cc < 2; cc++) {  // B: betaT 128 u-rows x 64 k
          int c = t + cc * 512;
          int r = c >> 3, c8 = c & 7;
          *(u16x8*)(Bh + r * LDS_P + c8 * 8) =
              *(const u16x8*)(betaTh + bt + (size_t)(n_base + r) * 1024 + kb + c8 * 8);
          *(u16x8*)(Bl + r * LDS_P + c8 * 8) =
              *(const u16x8*)(betaTl + bt + (size_t)(n_base + r) * 1024 + kb + c8 * 8);
        }
        __syncthreads();
#pragma unroll
        for (int kk = 0; kk < 64; kk += 32) {
          bf16x8 ah = __builtin_bit_cast(bf16x8, *(const u16x8*)(Ah + (msub * 16 + l16) * LDS_P + kk + quad * 8));
          bf16x8 al = __builtin_bit_cast(bf16x8, *(const u16x8*)(Al + (msub * 16 + l16) * LDS_P + kk + quad * 8));
#pragma unroll
          for (int tN = 0; tN < 4; tN++) {
            int brow = nsub * 64 + tN * 16 + l16;
            bf16x8 bh = __builtin_bit_cast(bf16x8, *(const u16x8*)(Bh + brow * LDS_P + kk + quad * 8));
            bf16x8 bl = __builtin_bit_cast(bf16x8, *(const u16x8*)(Bl + brow * LDS_P + kk + quad * 8));
            acc[tN] = __builtin_amdgcn_mfma_f32_16x16x32_bf16(ah, bh, acc[tN], 0, 0, 0);
            acc[tN] = __builtin_amdgcn_mfma_f32_16x16x32_bf16(ah, bl, acc[tN], 0, 0, 0);
            acc[tN] = __builtin_amdgcn_mfma_f32_16x16x32_bf16(al, bh, acc[tN], 0, 0, 0);
          }
        }
        __syncthreads();
      }
      const int mbase = m0 + msub * 16 + quad * 4;
#pragma unroll
      for (int tN = 0; tN < 4; tN++) {
        int u = n_base + nsub * 64 + tN * 16 + l16;
#pragma unroll
        for (int i = 0; i < 4; i++)
          agg[((size_t)b * 1024 + mbase + i) * 256 + u] = acc[tN][i];
      }
    }
    // drain agg stores before this block reads them back
    __asm__ volatile("s_waitcnt vmcnt(0)" ::: "memory");
    __syncthreads();

    // ---- xpre phase: two 64m x 128u halves on OWN agg rows ----
    const int r0 = b * 1024 + m0;
    for (int half = 0; half < 2; ++half) {
      const int n_base = half * 128;
      f32x4 acc[4];
#pragma unroll
      for (int i = 0; i < 4; i++) acc[i] = (f32x4){0.f, 0.f, 0.f, 0.f};

      for (int kb = 0; kb < 256; kb += 64) {
#pragma unroll
        for (int cc = 0; cc < 2; cc++) {  // A: agg 64 rows x 64 k, split
          int c = t + cc * 512;
          int r = c >> 4, c4 = c & 15;
          f32x4 vv = *(const f32x4*)(agg + (size_t)(r0 + r) * 256 + kb + c4 * 4);
          u16x4 hi, lo;
#pragma unroll
          for (int j = 0; j < 4; j++) {
            HiLo s = splitf(vv[j]);
            hi[j] = s.hi; lo[j] = s.lo;
          }
          *(u16x4*)(Ah + r * LDS_P + c4 * 4) = hi;
          *(u16x4*)(Al + r * LDS_P + c4 * 4) = lo;
        }
#pragma unroll
        for (int cc = 0; cc < 2; cc++) {  // B: WxT 128 u'-rows x 64 k
          int c = t + cc * 512;
          int r = c >> 3, c8 = c & 7;
          *(u16x8*)(Bh + r * LDS_P + c8 * 8) =
              *(const u16x8*)(Wxth + (size_t)(n_base + r) * 256 + kb + c8 * 8);
          *(u16x8*)(Bl + r * LDS_P + c8 * 8) =
              *(const u16x8*)(Wxtl + (size_t)(n_base + r) * 256 + kb + c8 * 8);
        }
        __syncthreads();
#pragma unroll
        for (int kk = 0; kk < 64; kk += 32) {
          bf16x8 ah = __builtin_bit_cast(bf16x8, *(const u16x8*)(Ah + (msub * 16 + l16) * LDS_P + kk + quad * 8));
          bf16x8 al = __builtin_bit_cast(bf16x8, *(const u16x8*)(Al + (msub * 16 + l16) * LDS_P + kk + quad * 8));
#pragma unroll
          for (int tN = 0; tN < 4; tN++) {
            int brow = nsub * 64 + tN * 16 + l16;
            bf16x8 bh = __builtin_bit_cast(bf16x8, *(const u16x8*)(Bh + brow * LDS_P + kk + quad * 8));
            bf16x8 bl = __builtin_bit_cast(bf16x8, *(const u16x8*)(Bl + brow * LDS_P + kk + quad * 8));
            acc[tN] = __builtin_amdgcn_mfma_f32_16x16x32_bf16(ah, bh, acc[tN], 0, 0, 0);
            acc[tN] = __builtin_amdgcn_mfma_f32_16x16x32_bf16(ah, bl, acc[tN], 0, 0, 0);
            acc[tN] = __builtin_amdgcn_mfma_f32_16x16x32_bf16(al, bh, acc[tN], 0, 0, 0);
          }
        }
        __syncthreads();
      }
      const int rbase = r0 + msub * 16 + quad * 4;  // b*1024 + m
      const int bI = rbase >> 10;
#pragma unroll
      for (int tN = 0; tN < 4; tN++) {
        int u = n_base + nsub * 64 + tN * 16 + l16;
        float bu = bias[u];
#pragma unroll
        for (int i = 0; i < 4; i++) {
          int mI = (rbase + i) & 1023;
          Xpre[((size_t)mI * 8 + bI) * 256 + u] = acc[tN][i] + bu;
        }
      }
    }
    // publish: drain stores, fence to agent scope, release-signal
    __asm__ volatile("s_waitcnt vmcnt(0)" ::: "memory");
    __syncthreads();
    if (t == 0) {
      __threadfence();
      __hip_atomic_fetch_add(&xpref[mtile], 1u, __ATOMIC_RELEASE,
                             __HIP_MEMORY_SCOPE_AGENT);
    }
    return;
  }

  // ====================== scan (R15 verbatim + spins) =======================
  const int b = pid - 128;
  const int w = t >> 6, lane = t & 63, quad = lane >> 4, l16 = lane & 15;
  const int colbase = w * 32;
  const bool epi = (quad < 2);           // quad0 -> tile0, quad1 -> tile1
  const int col_e = colbase + quad * 16 + l16;  // valid for epi lanes

  // Preload Wh hi+lo fragments: 2 n-tiles x 8 k-blocks, hi+lo
  bf16x8 bwh[2][8], bwl[2][8];
#pragma unroll
  for (int tN = 0; tN < 2; tN++) {
    const u16* wph = Whth + (size_t)(colbase + tN * 16 + l16) * 256 + quad * 8;
    const u16* wpl = Whtl + (size_t)(colbase + tN * 16 + l16) * 256 + quad * 8;
#pragma unroll
    for (int kb = 0; kb < 8; kb++) {
      bwh[tN][kb] = __builtin_bit_cast(bf16x8, *(const u16x8*)(wph + kb * 32));
      bwl[tN][kb] = __builtin_bit_cast(bf16x8, *(const u16x8*)(wpl + kb * 32));
    }
  }
  for (int i = t; i < 2 * 2 * HP_B; i += 512) ((u16*)h2)[i] = 0;

  // c banks 0..3: additive input for steps m4+0..m4+3 (epi lanes only).
  float cb[4];
  if (epi) {
    wait_tile(xpref, 0);               // Xpre rows 0..63 ready
#pragma unroll
    for (int k = 0; k < 4; k++) cb[k] = Xpre[(size_t)k * 2048 + b * 256 + col_e];
  }
  // Running pointers (advance by constants; no per-step re-derivation).
  const float* ldp = Xpre + 4 * 2048 + b * 256 + col_e;
  float* outp = out + (size_t)b * 262144 + col_e;
  // Hoisted LDS bases. Read base: row clamped to l16&1 (broadcast dup rows).
  const u16* rb0 = &h2[0][(l16 & 1) * HP_B + quad * 8];
  const u16* rb1 = &h2[1][(l16 & 1) * HP_B + quad * 8];
  u16* wb0 = &h2[0][0];
  u16* wb1 = &h2[1][0];
  __syncthreads();

  for (int m4 = 0; m4 < 1024; m4 += 4) {
#pragma unroll
    for (int k = 0; k < 4; k++) {
      const int p = k & 1;                       // compile-time in unrolled body
      const u16* rb = p ? rb1 : rb0;
      u16* hw = p ? wb0 : wb1;                   // write the other buffer

      // Hoist all 8 A-fragment reads (one lgkmcnt ramp, MFMAs pipeline).
      bf16x8 af[8];
#pragma unroll
      for (int kb = 0; kb < 8; kb++)
        af[kb] = __builtin_bit_cast(bf16x8, *(const u16x8*)(rb + kb * 32));

      f32x4 a0a = {0.f,0.f,0.f,0.f}, a0b = {0.f,0.f,0.f,0.f};
      f32x4 a1a = {0.f,0.f,0.f,0.f}, a1b = {0.f,0.f,0.f,0.f};
#pragma unroll
      for (int kb = 0; kb < 4; kb++) {
        a0a = __builtin_amdgcn_mfma_f32_16x16x32_bf16(af[kb], bwh[0][kb], a0a, 0, 0, 0);
        a1a = __builtin_amdgcn_mfma_f32_16x16x32_bf16(af[kb], bwh[1][kb], a1a, 0, 0, 0);
        a0b = __builtin_amdgcn_mfma_f32_16x16x32_bf16(af[kb + 4], bwh[0][kb + 4], a0b, 0, 0, 0);
        a1b = __builtin_amdgcn_mfma_f32_16x16x32_bf16(af[kb + 4], bwh[1][kb + 4], a1b, 0, 0, 0);
        a0a = __builtin_amdgcn_mfma_f32_16x16x32_bf16(af[kb], bwl[0][kb], a0a, 0, 0, 0);
        a1a = __builtin_amdgcn_mfma_f32_16x16x32_bf16(af[kb], bwl[1][kb], a1a, 0, 0, 0);
        a0b = __builtin_amdgcn_mfma_f32_16x16x32_bf16(af[kb + 4], bwl[0][kb + 4], a0b, 0, 0, 0);
        a1b = __builtin_amdgcn_mfma_f32_16x16x32_bf16(af[kb + 4], bwl[1][kb + 4], a1b, 0, 0, 0);
      }

      // Epilogue distributed: quad0 uses (a0a,a0b), quad1 uses (a1a,a1b).
      if (epi) {
        float sA0 = quad ? a1a[0] : a0a[0];
        float sA1 = quad ? a1a[1] : a0a[1];
        float sB0 = quad ? a1b[0] : a0b[0];
        float sB1 = quad ? a1b[1] : a0b[1];
        float hi_part = sA0 + sB0;
        float lo_part = sA1 + sB1;
        float x = (hi_part + lo_part) + cb[k];
        float y = tanh_fast(x);
        HiLo s = splitf(y);
        hw[col_e] = s.hi;           // row 0 = h_hi
        hw[HP_B + col_e] = s.lo;    // row 1 = h_lo
        *outp = y;                  // fire-and-forget (vmcnt never drained)
        // Prefetch c for step m+4 into the bank just consumed.
        if (m4 <= 1019 - k) {
          const int nr = m4 + k + 4;
          if ((nr & 63) == 0) wait_tile(xpref, nr >> 6);  // next Xpre tile
          cb[k] = *ldp;
          ldp += 2048;
        }
      }
      outp += 256;
      sync_lds_only();
    }
  }
}

extern "C" void kernel_launch(void* const* d_in, const int* in_sizes, int n_in,
                              void* d_out, int out_size, void* d_ws, size_t ws_size,
                              hipStream_t stream) {
  (void)in_sizes; (void)n_in; (void)out_size; (void)ws_size;
  const float* seq   = (const float*)d_in[0];  // (8,1024,256) f32
  const float* graph = (const float*)d_in[1];  // (8,1024,1024) f32
  const float* E     = (const float*)d_in[2];  // (256,256) f32
  const float* Wx    = (const float*)d_in[3];  // (256,256) f32
  const float* Wh    = (const float*)d_in[4];  // (256,256) f32
  const float* bias  = (const float*)d_in[5];  // (256,) f32
  float* out = (float*)d_out;                  // (8,1024,256) f32

  // workspace layout (bytes): ~26 MB total
  char* w = (char*)d_ws;
  float* rnorm  = (float*)(w + 0);          //  32 KB
  unsigned int* xpref = (unsigned int*)(w + 32768);  // 16 flags
  u16*   Wxth   = (u16*)(w + 294912);       // 128 KB each
  u16*   Wxtl   = (u16*)(w + 425984);
  u16*   Whth   = (u16*)(w + 557056);
  u16*   Whtl   = (u16*)(w + 688128);
  u16*   betaTh = (u16*)(w + 819200);       // 4 MB [b][u][l] (raw, no rnorm)
  u16*   betaTl = (u16*)(w + 5013504);      // 4 MB
  float* agg    = (float*)(w + 9207808);    // 8 MB [b][m][u]
  float* Xpre   = (float*)(w + 17596416);   // 8 MB [m][b][u]

  front1<<<1536, 512, 0, stream>>>(Wx, Wxth, Wxtl, Wh, Whth, Whtl,
                                   graph, rnorm, seq, E, betaTh, betaTl, xpref);
  back_fused<<<136, 512, 0, stream>>>(graph, betaTh, betaTl, rnorm, agg,
                                      Wxth, Wxtl, bias, Xpre,
                                      Whth, Whtl, out, xpref);
}

// Round 10
// 771.129 us; speedup vs baseline: 1.1174x; 1.1174x over previous
//
#include <hip/hip_runtime.h>
#include <hip/hip_bf16.h>

// GraphRNN, fp32 I/O (reference dtypes are float32).
// beta = (seq @ E) / rowsum(graph); agg = graph^T @ beta (per batch);
// Xpre = agg @ Wx + b; then 1024-step scan h = tanh(Xpre_m + h @ Wh).
// MFMA path: fp32 operands split into bf16 hi+lo (rel err ~2^-18).
//
// R21 = R19 revert + LDS XOR-swizzle on GEMM staging. R20 post-mortem:
// (a) producer/consumer fusion put mtile-0's full agg+xpre latency on the
// scan's critical path (+144us) -> reverted; (b) its profile exposed
// SQ_LDS_BANK_CONFLICT = 1.06e7 in the producer staging: the A-transpose
// scatter (u16 at row-stride 72 u16, rows spaced 4) lands 16 lanes on 2
// banks = 8-way conflict; beta's E-transpose up to 16-way. Fix: pitch-64
// tiles with bijective chunk-XOR  idx = row*64 + (col ^ x(row)<<3),
// x(row) = ((row>>2)^row)&7  — permutes 16B chunks within each row:
// transpose writes AND fragment reads both spread to >=8 bank-groups
// (2-way = free, m136). Applied to Ah/Al/Bh/Bl of beta/agg/xpre. Scan
// LDS untouched (0 conflicts, structure frozen since R15: R16/R17 edits
// both regressed). Pure address permutation -> bit-identical outputs.

typedef unsigned short u16;
typedef unsigned int u32;
typedef __bf16 bf16_t;
typedef __bf16 bf16x8 __attribute__((ext_vector_type(8)));
typedef float f32x4 __attribute__((ext_vector_type(4)));
typedef unsigned short u16x8 __attribute__((ext_vector_type(8)));
typedef unsigned short u16x4 __attribute__((ext_vector_type(4)));

#define HP_B  288  // h LDS row pitch (u16) in the scan

struct HiLo { u16 hi, lo; };

__device__ __forceinline__ u16 f2bf(float f) {
  bf16_t h = (bf16_t)f;  // RNE
  return __builtin_bit_cast(u16, h);
}
__device__ __forceinline__ HiLo splitf(float v) {
  bf16_t h = (bf16_t)v;
  HiLo r;
  r.hi = __builtin_bit_cast(u16, h);
  r.lo = f2bf(v - (float)h);
  return r;
}
__device__ __forceinline__ float tanh_fast(float x) {
  float ax = fabsf(x);
  float e  = __expf(-2.0f * ax);
  float t  = __fdividef(1.0f - e, 1.0f + e);
  return copysignf(t, x);
}
// Barrier with LDS-only visibility (drains lgkmcnt, not vmcnt).
__device__ __forceinline__ void sync_lds_only() {
  __asm__ volatile("s_waitcnt lgkmcnt(0)\ns_barrier" ::: "memory");
}
// Swizzled LDS index (u16 units): row pitch 64, 16B-chunk XOR within row.
// Bijective; keeps 8-u16 chunks contiguous and 16B-aligned.
__device__ __forceinline__ int swz64(int row, int col) {
  return (row << 6) + (col ^ ((((row >> 2) ^ row) & 7) << 3));
}

// ---------------- K1 front1 (512 thr): beta + weight splits + rowsums -------
// bid <  256 : raw betaT 64x128 stripe (dispatched FIRST — long poles).
// 256..511   : transpose+split Wx/Wh, 2 columns per block.
// 512..1535  : rnorm rows (bid-512)*8 .. +8 (one row per wave).
__global__ __launch_bounds__(512, 2) void front1(
    const float* __restrict__ Wx, u16* __restrict__ Wxth, u16* __restrict__ Wxtl,
    const float* __restrict__ Wh, u16* __restrict__ Whth, u16* __restrict__ Whtl,
    const float* __restrict__ graph, float* __restrict__ rnorm,
    const float* __restrict__ seq, const float* __restrict__ E,
    u16* __restrict__ betaTh, u16* __restrict__ betaTl) {
  __shared__ u16 Ah[64 * 64], Al[64 * 64];
  __shared__ u16 Bh[128 * 64], Bl[128 * 64];
  const int bid = blockIdx.x;
  const int t = threadIdx.x;

  if (bid >= 256 && bid < 512) {  // weight transpose+split, 2 cols/block
    const int wbid = bid - 256;
    const int u = ((wbid & 127) << 1) + (t >> 8), d = t & 255;
    const float* s; u16 *dh, *dl;
    if (wbid < 128) { s = Wx; dh = Wxth; dl = Wxtl; }
    else            { s = Wh; dh = Whth; dl = Whtl; }
    HiLo r = splitf(s[d * 256 + u]);
    dh[u * 256 + d] = r.hi;
    dl[u * 256 + d] = r.lo;
    return;
  }
  if (bid >= 512) {  // graph row-sums, 8 rows/block
    const int wave = t >> 6, lane = t & 63;
    const int row = (bid - 512) * 8 + wave;  // 0..8191
    const float* p = graph + (size_t)row * 1024 + lane * 16;
    float s = 0.f;
#pragma unroll
    for (int c = 0; c < 4; c++) {
      f32x4 v = *(const f32x4*)(p + c * 4);
#pragma unroll
      for (int j = 0; j < 4; j++) s += v[j];
    }
#pragma unroll
    for (int off = 32; off > 0; off >>= 1) s += __shfl_xor(s, off);
    if (lane == 0) rnorm[row] = 1.0f / fmaxf(s, 1e-7f);
    return;
  }

  // ---- raw beta (seq @ E): 64 rows x 128 u per block ----
  const int v = bid;                          // 0..255
  const int w = t >> 6, lane = t & 63, quad = lane >> 4, l16 = lane & 15;
  const int msub = w & 3, nsub = w >> 2;
  const int r0 = (v >> 1) * 64, n_base = (v & 1) * 128;
  f32x4 acc[4];
#pragma unroll
  for (int i = 0; i < 4; i++) acc[i] = (f32x4){0.f, 0.f, 0.f, 0.f};

  for (int kb = 0; kb < 256; kb += 64) {
#pragma unroll
    for (int cc = 0; cc < 2; cc++) {  // A: seq 64 rows x 64 k, split hi/lo
      int c = t + cc * 512;
      int r = c >> 4, c4 = c & 15;
      f32x4 vv = *(const f32x4*)(seq + (size_t)(r0 + r) * 256 + kb + c4 * 4);
      u16x4 hi, lo;
#pragma unroll
      for (int j = 0; j < 4; j++) {
        HiLo s = splitf(vv[j]);
        hi[j] = s.hi; lo[j] = s.lo;
      }
      *(u16x4*)(Ah + swz64(r, c4 * 4)) = hi;
      *(u16x4*)(Al + swz64(r, c4 * 4)) = lo;
    }
#pragma unroll
    for (int cc = 0; cc < 4; cc++) {  // B: E[d][u] 64 d x 128 u, transposed
      int c = t + cc * 512;
      int r = c >> 5, c5 = c & 31;    // r = d_local, c5 = u-chunk of 4
      f32x4 vv = *(const f32x4*)(E + (size_t)(kb + r) * 256 + n_base + c5 * 4);
#pragma unroll
      for (int j = 0; j < 4; j++) {
        HiLo s = splitf(vv[j]);
        Bh[swz64(c5 * 4 + j, r)] = s.hi;
        Bl[swz64(c5 * 4 + j, r)] = s.lo;
      }
    }
    __syncthreads();
#pragma unroll
    for (int kk = 0; kk < 64; kk += 32) {
      bf16x8 ah = __builtin_bit_cast(bf16x8, *(const u16x8*)(Ah + swz64(msub * 16 + l16, kk + quad * 8)));
      bf16x8 al = __builtin_bit_cast(bf16x8, *(const u16x8*)(Al + swz64(msub * 16 + l16, kk + quad * 8)));
#pragma unroll
      for (int tN = 0; tN < 4; tN++) {
        int brow = nsub * 64 + tN * 16 + l16;
        bf16x8 bh = __builtin_bit_cast(bf16x8, *(const u16x8*)(Bh + swz64(brow, kk + quad * 8)));
        bf16x8 bl = __builtin_bit_cast(bf16x8, *(const u16x8*)(Bl + swz64(brow, kk + quad * 8)));
        acc[tN] = __builtin_amdgcn_mfma_f32_16x16x32_bf16(ah, bh, acc[tN], 0, 0, 0);
        acc[tN] = __builtin_amdgcn_mfma_f32_16x16x32_bf16(ah, bl, acc[tN], 0, 0, 0);
        acc[tN] = __builtin_amdgcn_mfma_f32_16x16x32_bf16(al, bh, acc[tN], 0, 0, 0);
      }
    }
    __syncthreads();
  }
  const int rbase = r0 + msub * 16 + quad * 4;  // b*1024 + l
  const int bI = rbase >> 10, lI = rbase & 1023;
#pragma unroll
  for (int tN = 0; tN < 4; tN++) {
    int u = n_base + nsub * 64 + tN * 16 + l16;
    u16x4 hv, lv;
#pragma unroll
    for (int i = 0; i < 4; i++) {
      HiLo s = splitf(acc[tN][i]);   // raw beta (rnorm folded into agg)
      hv[i] = s.hi; lv[i] = s.lo;
    }
    size_t off = ((size_t)bI << 18) + (size_t)u * 1024 + lI;
    *(u16x4*)(betaTh + off) = hv;
    *(u16x4*)(betaTl + off) = lv;
  }
}

// ---------------- K2: agg[b][m][u] = sum_l (g[l][m]*rn[l]) * braw[l][u] -----
// 64 m x 128 u per block; A (graph^T, rn-folded) staged ONCE per stripe.
__global__ __launch_bounds__(512, 2) void gemm_agg(const float* __restrict__ graph,
                                                   const u16* __restrict__ betaTh,
                                                   const u16* __restrict__ betaTl,
                                                   const float* __restrict__ rnorm,
                                                   float* __restrict__ agg) {
  __shared__ u16 Ah[64 * 64], Al[64 * 64];
  __shared__ u16 Bh[128 * 64], Bl[128 * 64];
  const int t = threadIdx.x;
  const int w = t >> 6, lane = t & 63, quad = lane >> 4, l16 = lane & 15;
  const int msub = w & 3, nsub = w >> 2;
  const int m0 = blockIdx.x * 64, n_base = blockIdx.y * 128, b = blockIdx.z;
  const float* g = graph + (size_t)b * (1024 * 1024);
  const float* rnb = rnorm + b * 1024;
  const size_t bt = (size_t)b << 18;
  f32x4 acc[4];
#pragma unroll
  for (int i = 0; i < 4; i++) acc[i] = (f32x4){0.f, 0.f, 0.f, 0.f};

  for (int kb = 0; kb < 1024; kb += 64) {
#pragma unroll
    for (int cc = 0; cc < 2; cc++) {  // A: graph 64 l x 64 m, transposed+rn
      int c = t + cc * 512;
      int r = c >> 4, c4 = c & 15;    // r = l_local, c4 = m-chunk of 4
      f32x4 vv = *(const f32x4*)(g + (size_t)(kb + r) * 1024 + m0 + c4 * 4);
      float rn = rnb[kb + r];
#pragma unroll
      for (int j = 0; j < 4; j++) {
        HiLo s = splitf(vv[j] * rn);
        Ah[swz64(c4 * 4 + j, r)] = s.hi;  // A[m][l]
        Al[swz64(c4 * 4 + j, r)] = s.lo;
      }
    }
#pragma unroll
    for (int cc = 0; cc < 2; cc++) {  // B: betaT 128 u-rows x 64 k copy
      int c = t + cc * 512;
      int r = c >> 3, c8 = c & 7;
      *(u16x8*)(Bh + swz64(r, c8 * 8)) =
          *(const u16x8*)(betaTh + bt + (size_t)(n_base + r) * 1024 + kb + c8 * 8);
      *(u16x8*)(Bl + swz64(r, c8 * 8)) =
          *(const u16x8*)(betaTl + bt + (size_t)(n_base + r) * 1024 + kb + c8 * 8);
    }
    __syncthreads();
#pragma unroll
    for (int kk = 0; kk < 64; kk += 32) {
      bf16x8 ah = __builtin_bit_cast(bf16x8, *(const u16x8*)(Ah + swz64(msub * 16 + l16, kk + quad * 8)));
      bf16x8 al = __builtin_bit_cast(bf16x8, *(const u16x8*)(Al + swz64(msub * 16 + l16, kk + quad * 8)));
#pragma unroll
      for (int tN = 0; tN < 4; tN++) {
        int brow = nsub * 64 + tN * 16 + l16;
        bf16x8 bh = __builtin_bit_cast(bf16x8, *(const u16x8*)(Bh + swz64(brow, kk + quad * 8)));
        bf16x8 bl = __builtin_bit_cast(bf16x8, *(const u16x8*)(Bl + swz64(brow, kk + quad * 8)));
        acc[tN] = __builtin_amdgcn_mfma_f32_16x16x32_bf16(ah, bh, acc[tN], 0, 0, 0);
        acc[tN] = __builtin_amdgcn_mfma_f32_16x16x32_bf16(ah, bl, acc[tN], 0, 0, 0);
        acc[tN] = __builtin_amdgcn_mfma_f32_16x16x32_bf16(al, bh, acc[tN], 0, 0, 0);
      }
    }
    __syncthreads();
  }
  const int mbase = m0 + msub * 16 + quad * 4;
#pragma unroll
  for (int tN = 0; tN < 4; tN++) {
    int u = n_base + nsub * 64 + tN * 16 + l16;
#pragma unroll
    for (int i = 0; i < 4; i++)
      agg[((size_t)b * 1024 + mbase + i) * 256 + u] = acc[tN][i];
  }
}

// ---------------- K3: Xpre[m][b][u] = (agg @ Wx)[b,m,u] + bias[u] -----------
__global__ __launch_bounds__(512, 2) void gemm_xpre(const float* __restrict__ agg,
                                                    const u16* __restrict__ Wxth,
                                                    const u16* __restrict__ Wxtl,
                                                    const float* __restrict__ bias,
                                                    float* __restrict__ Xpre) {
  __shared__ u16 Ah[64 * 64], Al[64 * 64];
  __shared__ u16 Bh[128 * 64], Bl[128 * 64];
  const int t = threadIdx.x;
  const int w = t >> 6, lane = t & 63, quad = lane >> 4, l16 = lane & 15;
  const int msub = w & 3, nsub = w >> 2;
  const int r0 = blockIdx.x * 64, n_base = blockIdx.y * 128;
  f32x4 acc[4];
#pragma unroll
  for (int i = 0; i < 4; i++) acc[i] = (f32x4){0.f, 0.f, 0.f, 0.f};

  for (int kb = 0; kb < 256; kb += 64) {
#pragma unroll
    for (int cc = 0; cc < 2; cc++) {  // A: agg 64 rows x 64 k, split hi/lo
      int c = t + cc * 512;
      int r = c >> 4, c4 = c & 15;
      f32x4 vv = *(const f32x4*)(agg + (size_t)(r0 + r) * 256 + kb + c4 * 4);
      u16x4 hi, lo;
#pragma unroll
      for (int j = 0; j < 4; j++) {
        HiLo s = splitf(vv[j]);
        hi[j] = s.hi; lo[j] = s.lo;
      }
      *(u16x4*)(Ah + swz64(r, c4 * 4)) = hi;
      *(u16x4*)(Al + swz64(r, c4 * 4)) = lo;
    }
#pragma unroll
    for (int cc = 0; cc < 2; cc++) {  // B: WxT 128 u'-rows x 64 k copy
      int c = t + cc * 512;
      int r = c >> 3, c8 = c & 7;
      *(u16x8*)(Bh + swz64(r, c8 * 8)) =
          *(const u16x8*)(Wxth + (size_t)(n_base + r) * 256 + kb + c8 * 8);
      *(u16x8*)(Bl + swz64(r, c8 * 8)) =
          *(const u16x8*)(Wxtl + (size_t)(n_base + r) * 256 + kb + c8 * 8);
    }
    __syncthreads();
#pragma unroll
    for (int kk = 0; kk < 64; kk += 32) {
      bf16x8 ah = __builtin_bit_cast(bf16x8, *(const u16x8*)(Ah + swz64(msub * 16 + l16, kk + quad * 8)));
      bf16x8 al = __builtin_bit_cast(bf16x8, *(const u16x8*)(Al + swz64(msub * 16 + l16, kk + quad * 8)));
#pragma unroll
      for (int tN = 0; tN < 4; tN++) {
        int brow = nsub * 64 + tN * 16 + l16;
        bf16x8 bh = __builtin_bit_cast(bf16x8, *(const u16x8*)(Bh + swz64(brow, kk + quad * 8)));
        bf16x8 bl = __builtin_bit_cast(bf16x8, *(const u16x8*)(Bl + swz64(brow, kk + quad * 8)));
        acc[tN] = __builtin_amdgcn_mfma_f32_16x16x32_bf16(ah, bh, acc[tN], 0, 0, 0);
        acc[tN] = __builtin_amdgcn_mfma_f32_16x16x32_bf16(ah, bl, acc[tN], 0, 0, 0);
        acc[tN] = __builtin_amdgcn_mfma_f32_16x16x32_bf16(al, bh, acc[tN], 0, 0, 0);
      }
    }
    __syncthreads();
  }
  const int rbase = r0 + msub * 16 + quad * 4;  // b*1024 + m
  const int bI = rbase >> 10;
#pragma unroll
  for (int tN = 0; tN < 4; tN++) {
    int u = n_base + nsub * 64 + tN * 16 + l16;
    float bu = bias[u];
#pragma unroll
    for (int i = 0; i < 4; i++) {
      int mI = (rbase + i) & 1023;
      Xpre[((size_t)mI * 8 + bI) * 256 + u] = acc[tN][i] + bu;
    }
  }
}

// ---------------- K4: sequential scan — R15 VERBATIM (622us proven) ---------
// 8 WGs (1 batch each), 8 waves. Wave w owns cols [w*32,w*32+32) = 2
// n-tiles. A-tile: 2 rows (h hi/lo), read row clamped to l16&1 ->
// broadcast, conflict-free. Quads 0/1 both hold valid (hi,lo) in C regs
// [0],[1]; quad0 -> tile0, quad1 -> tile1 -> 1 tanh chain/lane. MFMA
// interleave keeps 4 independent accumulator chains (a0a,a1a,a0b,a1b) —
// REQUIRED (R17: 2 chains exposed MFMA latency, +35%). All 8 ds_reads
// hoisted to step top. Nothing precedes MFMA issue (R16 lesson).
__global__ __launch_bounds__(512, 2) void rnn_scan(const u16* __restrict__ Whth,
                                                   const u16* __restrict__ Whtl,
                                                   const float* __restrict__ Xpre,
                                                   float* __restrict__ out) {
  __shared__ u16 h2[2][2 * HP_B];
  const int b = blockIdx.x;
  const int t = threadIdx.x;
  const int w = t >> 6, lane = t & 63, quad = lane >> 4, l16 = lane & 15;
  const int colbase = w * 32;
  const bool epi = (quad < 2);           // quad0 -> tile0, quad1 -> tile1
  const int col_e = colbase + quad * 16 + l16;  // valid for epi lanes

  // Preload Wh hi+lo fragments: 2 n-tiles x 8 k-blocks, hi+lo
  bf16x8 bwh[2][8], bwl[2][8];
#pragma unroll
  for (int tN = 0; tN < 2; tN++) {
    const u16* wph = Whth + (size_t)(colbase + tN * 16 + l16) * 256 + quad * 8;
    const u16* wpl = Whtl + (size_t)(colbase + tN * 16 + l16) * 256 + quad * 8;
#pragma unroll
    for (int kb = 0; kb < 8; kb++) {
      bwh[tN][kb] = __builtin_bit_cast(bf16x8, *(const u16x8*)(wph + kb * 32));
      bwl[tN][kb] = __builtin_bit_cast(bf16x8, *(const u16x8*)(wpl + kb * 32));
    }
  }
  for (int i = t; i < 2 * 2 * HP_B; i += 512) ((u16*)h2)[i] = 0;

  // c banks 0..3: additive input for steps m4+0..m4+3 (epi lanes only).
  float cb[4];
  if (epi) {
#pragma unroll
    for (int k = 0; k < 4; k++) cb[k] = Xpre[(size_t)k * 2048 + b * 256 + col_e];
  }
  // Running pointers (advance by constants; no per-step re-derivation).
  const float* ldp = Xpre + 4 * 2048 + b * 256 + col_e;
  float* outp = out + (size_t)b * 262144 + col_e;
  // Hoisted LDS bases. Read base: row clamped to l16&1 (broadcast dup rows).
  const u16* rb0 = &h2[0][(l16 & 1) * HP_B + quad * 8];
  const u16* rb1 = &h2[1][(l16 & 1) * HP_B + quad * 8];
  u16* wb0 = &h2[0][0];
  u16* wb1 = &h2[1][0];
  __syncthreads();

  for (int m4 = 0; m4 < 1024; m4 += 4) {
#pragma unroll
    for (int k = 0; k < 4; k++) {
      const int p = k & 1;                       // compile-time in unrolled body
      const u16* rb = p ? rb1 : rb0;
      u16* hw = p ? wb0 : wb1;                   // write the other buffer

      // Hoist all 8 A-fragment reads (one lgkmcnt ramp, MFMAs pipeline).
      bf16x8 af[8];
#pragma unroll
      for (int kb = 0; kb < 8; kb++)
        af[kb] = __builtin_bit_cast(bf16x8, *(const u16x8*)(rb + kb * 32));

      f32x4 a0a = {0.f,0.f,0.f,0.f}, a0b = {0.f,0.f,0.f,0.f};
      f32x4 a1a = {0.f,0.f,0.f,0.f}, a1b = {0.f,0.f,0.f,0.f};
#pragma unroll
      for (int kb = 0; kb < 4; kb++) {
        a0a = __builtin_amdgcn_mfma_f32_16x16x32_bf16(af[kb], bwh[0][kb], a0a, 0, 0, 0);
        a1a = __builtin_amdgcn_mfma_f32_16x16x32_bf16(af[kb], bwh[1][kb], a1a, 0, 0, 0);
        a0b = __builtin_amdgcn_mfma_f32_16x16x32_bf16(af[kb + 4], bwh[0][kb + 4], a0b, 0, 0, 0);
        a1b = __builtin_amdgcn_mfma_f32_16x16x32_bf16(af[kb + 4], bwh[1][kb + 4], a1b, 0, 0, 0);
        a0a = __builtin_amdgcn_mfma_f32_16x16x32_bf16(af[kb], bwl[0][kb], a0a, 0, 0, 0);
        a1a = __builtin_amdgcn_mfma_f32_16x16x32_bf16(af[kb], bwl[1][kb], a1a, 0, 0, 0);
        a0b = __builtin_amdgcn_mfma_f32_16x16x32_bf16(af[kb + 4], bwl[0][kb + 4], a0b, 0, 0, 0);
        a1b = __builtin_amdgcn_mfma_f32_16x16x32_bf16(af[kb + 4], bwl[1][kb + 4], a1b, 0, 0, 0);
      }

      // Epilogue distributed: quad0 uses (a0a,a0b), quad1 uses (a1a,a1b).
      if (epi) {
        float sA0 = quad ? a1a[0] : a0a[0];
        float sA1 = quad ? a1a[1] : a0a[1];
        float sB0 = quad ? a1b[0] : a0b[0];
        float sB1 = quad ? a1b[1] : a0b[1];
        float hi_part = sA0 + sB0;
        float lo_part = sA1 + sB1;
        float x = (hi_part + lo_part) + cb[k];
        float y = tanh_fast(x);
        HiLo s = splitf(y);
        hw[col_e] = s.hi;           // row 0 = h_hi
        hw[HP_B + col_e] = s.lo;    // row 1 = h_lo
        *outp = y;                  // fire-and-forget (vmcnt never drained)
        // Prefetch c for step m+4 into the bank just consumed.
        if (m4 <= 1019 - k) {
          cb[k] = *ldp;
          ldp += 2048;
        }
      }
      outp += 256;
      sync_lds_only();
    }
  }
}

extern "C" void kernel_launch(void* const* d_in, const int* in_sizes, int n_in,
                              void* d_out, int out_size, void* d_ws, size_t ws_size,
                              hipStream_t stream) {
  (void)in_sizes; (void)n_in; (void)out_size; (void)ws_size;
  const float* seq   = (const float*)d_in[0];  // (8,1024,256) f32
  const float* graph = (const float*)d_in[1];  // (8,1024,1024) f32
  const float* E     = (const float*)d_in[2];  // (256,256) f32
  const float* Wx    = (const float*)d_in[3];  // (256,256) f32
  const float* Wh    = (const float*)d_in[4];  // (256,256) f32
  const float* bias  = (const float*)d_in[5];  // (256,) f32
  float* out = (float*)d_out;                  // (8,1024,256) f32

  // workspace layout (bytes): ~26 MB total
  char* w = (char*)d_ws;
  float* rnorm  = (float*)(w + 0);          //  32 KB
  u16*   Wxth   = (u16*)(w + 294912);       // 128 KB each
  u16*   Wxtl   = (u16*)(w + 425984);
  u16*   Whth   = (u16*)(w + 557056);
  u16*   Whtl   = (u16*)(w + 688128);
  u16*   betaTh = (u16*)(w + 819200);       // 4 MB [b][u][l] (raw, no rnorm)
  u16*   betaTl = (u16*)(w + 5013504);      // 4 MB
  float* agg    = (float*)(w + 9207808);    // 8 MB [b][m][u]
  float* Xpre   = (float*)(w + 17596416);   // 8 MB [m][b][u]

  front1<<<1536, 512, 0, stream>>>(Wx, Wxth, Wxtl, Wh, Whth, Whtl,
                                   graph, rnorm, seq, E, betaTh, betaTl);
  gemm_agg<<<dim3(16, 2, 8), 512, 0, stream>>>(graph, betaTh, betaTl, rnorm, agg);
  gemm_xpre<<<dim3(128, 2), 512, 0, stream>>>(agg, Wxth, Wxtl, bias, Xpre);
  rnn_scan<<<dim3(8), 512, 0, stream>>>(Whth, Whtl, Xpre, out);
}

// Round 11
// 747.302 us; speedup vs baseline: 1.1530x; 1.0319x over previous
//
#include <hip/hip_runtime.h>
#include <hip/hip_bf16.h>

// GraphRNN, fp32 I/O (reference dtypes are float32).
// beta = (seq @ E) / rowsum(graph); agg = graph^T @ beta (per batch);
// Xpre = agg @ Wx + b; then 1024-step scan h = tanh(Xpre_m + h @ Wh).
// MFMA path: fp32 operands split into bf16 hi+lo (rel err ~2^-18).
//
// R22 = R21 + explicit cross-iteration register prefetch in the GEMM
// stagings. Evidence chain: front ~147us invariant under launch-merge
// (R18), work-dedup (R19, -16), bank-swizzle (R21, null though geometry
// provably fixed) -> the cost is EXPOSED GLOBAL-LOAD LATENCY: 512-thr
// blocks at 1 block/CU phase-lock all waves behind shared barriers, so
// each K-iter serially pays an HBM round trip (~900cy) before staging
// (gemm_agg measured ~7.9Kcy/iter via R20's producer latency). Fix:
// K-loop restructured to {write regs->LDS; barrier; issue NEXT tile's
// loads into regs; MFMA; barrier} — load latency hides under ~930cy of
// MFMA issue. Same values, same splitf order, same LDS addresses ->
// bit-identical. Scan = R15 verbatim (623us; frozen — R16/R17 edits
// regressed). Swizzle swz64 kept from R21.

typedef unsigned short u16;
typedef unsigned int u32;
typedef __bf16 bf16_t;
typedef __bf16 bf16x8 __attribute__((ext_vector_type(8)));
typedef float f32x4 __attribute__((ext_vector_type(4)));
typedef unsigned short u16x8 __attribute__((ext_vector_type(8)));
typedef unsigned short u16x4 __attribute__((ext_vector_type(4)));

#define HP_B  288  // h LDS row pitch (u16) in the scan

struct HiLo { u16 hi, lo; };

__device__ __forceinline__ u16 f2bf(float f) {
  bf16_t h = (bf16_t)f;  // RNE
  return __builtin_bit_cast(u16, h);
}
__device__ __forceinline__ HiLo splitf(float v) {
  bf16_t h = (bf16_t)v;
  HiLo r;
  r.hi = __builtin_bit_cast(u16, h);
  r.lo = f2bf(v - (float)h);
  return r;
}
__device__ __forceinline__ float tanh_fast(float x) {
  float ax = fabsf(x);
  float e  = __expf(-2.0f * ax);
  float t  = __fdividef(1.0f - e, 1.0f + e);
  return copysignf(t, x);
}
// Barrier with LDS-only visibility (drains lgkmcnt, not vmcnt).
__device__ __forceinline__ void sync_lds_only() {
  __asm__ volatile("s_waitcnt lgkmcnt(0)\ns_barrier" ::: "memory");
}
// Swizzled LDS index (u16 units): row pitch 64, 16B-chunk XOR within row.
// Bijective; keeps >=8B-aligned groups contiguous.
__device__ __forceinline__ int swz64(int row, int col) {
  return (row << 6) + (col ^ ((((row >> 2) ^ row) & 7) << 3));
}

// ---------------- K1 front1 (512 thr): beta + weight splits + rowsums -------
// bid <  256 : raw betaT 64x128 stripe (dispatched FIRST — long poles).
// 256..511   : transpose+split Wx/Wh, 2 columns per block.
// 512..1535  : rnorm rows (bid-512)*8 .. +8 (one row per wave).
__global__ __launch_bounds__(512, 2) void front1(
    const float* __restrict__ Wx, u16* __restrict__ Wxth, u16* __restrict__ Wxtl,
    const float* __restrict__ Wh, u16* __restrict__ Whth, u16* __restrict__ Whtl,
    const float* __restrict__ graph, float* __restrict__ rnorm,
    const float* __restrict__ seq, const float* __restrict__ E,
    u16* __restrict__ betaTh, u16* __restrict__ betaTl) {
  __shared__ u16 Ah[64 * 64], Al[64 * 64];
  __shared__ u16 Bh[128 * 64], Bl[128 * 64];
  const int bid = blockIdx.x;
  const int t = threadIdx.x;

  if (bid >= 256 && bid < 512) {  // weight transpose+split, 2 cols/block
    const int wbid = bid - 256;
    const int u = ((wbid & 127) << 1) + (t >> 8), d = t & 255;
    const float* s; u16 *dh, *dl;
    if (wbid < 128) { s = Wx; dh = Wxth; dl = Wxtl; }
    else            { s = Wh; dh = Whth; dl = Whtl; }
    HiLo r = splitf(s[d * 256 + u]);
    dh[u * 256 + d] = r.hi;
    dl[u * 256 + d] = r.lo;
    return;
  }
  if (bid >= 512) {  // graph row-sums, 8 rows/block
    const int wave = t >> 6, lane = t & 63;
    const int row = (bid - 512) * 8 + wave;  // 0..8191
    const float* p = graph + (size_t)row * 1024 + lane * 16;
    float s = 0.f;
#pragma unroll
    for (int c = 0; c < 4; c++) {
      f32x4 v = *(const f32x4*)(p + c * 4);
#pragma unroll
      for (int j = 0; j < 4; j++) s += v[j];
    }
#pragma unroll
    for (int off = 32; off > 0; off >>= 1) s += __shfl_xor(s, off);
    if (lane == 0) rnorm[row] = 1.0f / fmaxf(s, 1e-7f);
    return;
  }

  // ---- raw beta (seq @ E): 64 rows x 128 u per block, prefetched ----
  const int v = bid;                          // 0..255
  const int w = t >> 6, lane = t & 63, quad = lane >> 4, l16 = lane & 15;
  const int msub = w & 3, nsub = w >> 2;
  const int r0 = (v >> 1) * 64, n_base = (v & 1) * 128;
  f32x4 acc[4];
#pragma unroll
  for (int i = 0; i < 4; i++) acc[i] = (f32x4){0.f, 0.f, 0.f, 0.f};

  f32x4 rA[2], rB[4];
  // prologue loads, kb = 0
#pragma unroll
  for (int cc = 0; cc < 2; cc++) {
    int c = t + cc * 512;
    int r = c >> 4, c4 = c & 15;
    rA[cc] = *(const f32x4*)(seq + (size_t)(r0 + r) * 256 + c4 * 4);
  }
#pragma unroll
  for (int cc = 0; cc < 4; cc++) {
    int c = t + cc * 512;
    int r = c >> 5, c5 = c & 31;
    rB[cc] = *(const f32x4*)(E + (size_t)r * 256 + n_base + c5 * 4);
  }

  for (int kb = 0; kb < 256; kb += 64) {
    // ---- write phase (regs -> LDS; same values/order as R21) ----
#pragma unroll
    for (int cc = 0; cc < 2; cc++) {  // A: seq rows, split hi/lo
      int c = t + cc * 512;
      int r = c >> 4, c4 = c & 15;
      u16x4 hi, lo;
#pragma unroll
      for (int j = 0; j < 4; j++) {
        HiLo s = splitf(rA[cc][j]);
        hi[j] = s.hi; lo[j] = s.lo;
      }
      *(u16x4*)(Ah + swz64(r, c4 * 4)) = hi;
      *(u16x4*)(Al + swz64(r, c4 * 4)) = lo;
    }
#pragma unroll
    for (int cc = 0; cc < 4; cc++) {  // B: E transposed [u][d]
      int c = t + cc * 512;
      int r = c >> 5, c5 = c & 31;
#pragma unroll
      for (int j = 0; j < 4; j++) {
        HiLo s = splitf(rB[cc][j]);
        Bh[swz64(c5 * 4 + j, r)] = s.hi;
        Bl[swz64(c5 * 4 + j, r)] = s.lo;
      }
    }
    __syncthreads();
    // ---- prefetch next K-tile (overlaps MFMA below) ----
    if (kb + 64 < 256) {
      const int kn = kb + 64;
#pragma unroll
      for (int cc = 0; cc < 2; cc++) {
        int c = t + cc * 512;
        int r = c >> 4, c4 = c & 15;
        rA[cc] = *(const f32x4*)(seq + (size_t)(r0 + r) * 256 + kn + c4 * 4);
      }
#pragma unroll
      for (int cc = 0; cc < 4; cc++) {
        int c = t + cc * 512;
        int r = c >> 5, c5 = c & 31;
        rB[cc] = *(const f32x4*)(E + (size_t)(kn + r) * 256 + n_base + c5 * 4);
      }
    }
    // ---- MFMA phase ----
#pragma unroll
    for (int kk = 0; kk < 64; kk += 32) {
      bf16x8 ah = __builtin_bit_cast(bf16x8, *(const u16x8*)(Ah + swz64(msub * 16 + l16, kk + quad * 8)));
      bf16x8 al = __builtin_bit_cast(bf16x8, *(const u16x8*)(Al + swz64(msub * 16 + l16, kk + quad * 8)));
#pragma unroll
      for (int tN = 0; tN < 4; tN++) {
        int brow = nsub * 64 + tN * 16 + l16;
        bf16x8 bh = __builtin_bit_cast(bf16x8, *(const u16x8*)(Bh + swz64(brow, kk + quad * 8)));
        bf16x8 bl = __builtin_bit_cast(bf16x8, *(const u16x8*)(Bl + swz64(brow, kk + quad * 8)));
        acc[tN] = __builtin_amdgcn_mfma_f32_16x16x32_bf16(ah, bh, acc[tN], 0, 0, 0);
        acc[tN] = __builtin_amdgcn_mfma_f32_16x16x32_bf16(ah, bl, acc[tN], 0, 0, 0);
        acc[tN] = __builtin_amdgcn_mfma_f32_16x16x32_bf16(al, bh, acc[tN], 0, 0, 0);
      }
    }
    __syncthreads();
  }
  const int rbase = r0 + msub * 16 + quad * 4;  // b*1024 + l
  const int bI = rbase >> 10, lI = rbase & 1023;
#pragma unroll
  for (int tN = 0; tN < 4; tN++) {
    int u = n_base + nsub * 64 + tN * 16 + l16;
    u16x4 hv, lv;
#pragma unroll
    for (int i = 0; i < 4; i++) {
      HiLo s = splitf(acc[tN][i]);   // raw beta (rnorm folded into agg)
      hv[i] = s.hi; lv[i] = s.lo;
    }
    size_t off = ((size_t)bI << 18) + (size_t)u * 1024 + lI;
    *(u16x4*)(betaTh + off) = hv;
    *(u16x4*)(betaTl + off) = lv;
  }
}

// ---------------- K2: agg[b][m][u] = sum_l (g[l][m]*rn[l]) * braw[l][u] -----
// 64 m x 128 u per block; A (graph^T, rn-folded) staged ONCE; prefetched.
__global__ __launch_bounds__(512, 2) void gemm_agg(const float* __restrict__ graph,
                                                   const u16* __restrict__ betaTh,
                                                   const u16* __restrict__ betaTl,
                                                   const float* __restrict__ rnorm,
                                                   float* __restrict__ agg) {
  __shared__ u16 Ah[64 * 64], Al[64 * 64];
  __shared__ u16 Bh[128 * 64], Bl[128 * 64];
  const int t = threadIdx.x;
  const int w = t >> 6, lane = t & 63, quad = lane >> 4, l16 = lane & 15;
  const int msub = w & 3, nsub = w >> 2;
  const int m0 = blockIdx.x * 64, n_base = blockIdx.y * 128, b = blockIdx.z;
  const float* g = graph + (size_t)b * (1024 * 1024);
  const float* rnb = rnorm + b * 1024;
  const size_t bt = (size_t)b << 18;
  f32x4 acc[4];
#pragma unroll
  for (int i = 0; i < 4; i++) acc[i] = (f32x4){0.f, 0.f, 0.f, 0.f};

  f32x4 rA[2]; float rRn[2]; u16x8 rBh[2], rBl[2];
  // prologue loads, kb = 0
#pragma unroll
  for (int cc = 0; cc < 2; cc++) {
    int c = t + cc * 512;
    int r = c >> 4, c4 = c & 15;
    rA[cc] = *(const f32x4*)(g + (size_t)r * 1024 + m0 + c4 * 4);
    rRn[cc] = rnb[r];
  }
#pragma unroll
  for (int cc = 0; cc < 2; cc++) {
    int c = t + cc * 512;
    int r = c >> 3, c8 = c & 7;
    rBh[cc] = *(const u16x8*)(betaTh + bt + (size_t)(n_base + r) * 1024 + c8 * 8);
    rBl[cc] = *(const u16x8*)(betaTl + bt + (size_t)(n_base + r) * 1024 + c8 * 8);
  }

  for (int kb = 0; kb < 1024; kb += 64) {
    // ---- write phase ----
#pragma unroll
    for (int cc = 0; cc < 2; cc++) {  // A: graph^T * rn (same op order)
      int c = t + cc * 512;
      int r = c >> 4, c4 = c & 15;
#pragma unroll
      for (int j = 0; j < 4; j++) {
        HiLo s = splitf(rA[cc][j] * rRn[cc]);
        Ah[swz64(c4 * 4 + j, r)] = s.hi;  // A[m][l]
        Al[swz64(c4 * 4 + j, r)] = s.lo;
      }
    }
#pragma unroll
    for (int cc = 0; cc < 2; cc++) {  // B: betaT copy
      int c = t + cc * 512;
      int r = c >> 3, c8 = c & 7;
      *(u16x8*)(Bh + swz64(r, c8 * 8)) = rBh[cc];
      *(u16x8*)(Bl + swz64(r, c8 * 8)) = rBl[cc];
    }
    __syncthreads();
    // ---- prefetch next K-tile (overlaps MFMA) ----
    if (kb + 64 < 1024) {
      const int kn = kb + 64;
#pragma unroll
      for (int cc = 0; cc < 2; cc++) {
        int c = t + cc * 512;
        int r = c >> 4, c4 = c & 15;
        rA[cc] = *(const f32x4*)(g + (size_t)(kn + r) * 1024 + m0 + c4 * 4);
        rRn[cc] = rnb[kn + r];
      }
#pragma unroll
      for (int cc = 0; cc < 2; cc++) {
        int c = t + cc * 512;
        int r = c >> 3, c8 = c & 7;
        rBh[cc] = *(const u16x8*)(betaTh + bt + (size_t)(n_base + r) * 1024 + kn + c8 * 8);
        rBl[cc] = *(const u16x8*)(betaTl + bt + (size_t)(n_base + r) * 1024 + kn + c8 * 8);
      }
    }
    // ---- MFMA phase ----
#pragma unroll
    for (int kk = 0; kk < 64; kk += 32) {
      bf16x8 ah = __builtin_bit_cast(bf16x8, *(const u16x8*)(Ah + swz64(msub * 16 + l16, kk + quad * 8)));
      bf16x8 al = __builtin_bit_cast(bf16x8, *(const u16x8*)(Al + swz64(msub * 16 + l16, kk + quad * 8)));
#pragma unroll
      for (int tN = 0; tN < 4; tN++) {
        int brow = nsub * 64 + tN * 16 + l16;
        bf16x8 bh = __builtin_bit_cast(bf16x8, *(const u16x8*)(Bh + swz64(brow, kk + quad * 8)));
        bf16x8 bl = __builtin_bit_cast(bf16x8, *(const u16x8*)(Bl + swz64(brow, kk + quad * 8)));
        acc[tN] = __builtin_amdgcn_mfma_f32_16x16x32_bf16(ah, bh, acc[tN], 0, 0, 0);
        acc[tN] = __builtin_amdgcn_mfma_f32_16x16x32_bf16(ah, bl, acc[tN], 0, 0, 0);
        acc[tN] = __builtin_amdgcn_mfma_f32_16x16x32_bf16(al, bh, acc[tN], 0, 0, 0);
      }
    }
    __syncthreads();
  }
  const int mbase = m0 + msub * 16 + quad * 4;
#pragma unroll
  for (int tN = 0; tN < 4; tN++) {
    int u = n_base + nsub * 64 + tN * 16 + l16;
#pragma unroll
    for (int i = 0; i < 4; i++)
      agg[((size_t)b * 1024 + mbase + i) * 256 + u] = acc[tN][i];
  }
}

// ---------------- K3: Xpre[m][b][u] = (agg @ Wx)[b,m,u] + bias[u] -----------
__global__ __launch_bounds__(512, 2) void gemm_xpre(const float* __restrict__ agg,
                                                    const u16* __restrict__ Wxth,
                                                    const u16* __restrict__ Wxtl,
                                                    const float* __restrict__ bias,
                                                    float* __restrict__ Xpre) {
  __shared__ u16 Ah[64 * 64], Al[64 * 64];
  __shared__ u16 Bh[128 * 64], Bl[128 * 64];
  const int t = threadIdx.x;
  const int w = t >> 6, lane = t & 63, quad = lane >> 4, l16 = lane & 15;
  const int msub = w & 3, nsub = w >> 2;
  const int r0 = blockIdx.x * 64, n_base = blockIdx.y * 128;
  f32x4 acc[4];
#pragma unroll
  for (int i = 0; i < 4; i++) acc[i] = (f32x4){0.f, 0.f, 0.f, 0.f};

  f32x4 rA[2]; u16x8 rBh[2], rBl[2];
  // prologue loads, kb = 0
#pragma unroll
  for (int cc = 0; cc < 2; cc++) {
    int c = t + cc * 512;
    int r = c >> 4, c4 = c & 15;
    rA[cc] = *(const f32x4*)(agg + (size_t)(r0 + r) * 256 + c4 * 4);
  }
#pragma unroll
  for (int cc = 0; cc < 2; cc++) {
    int c = t + cc * 512;
    int r = c >> 3, c8 = c & 7;
    rBh[cc] = *(const u16x8*)(Wxth + (size_t)(n_base + r) * 256 + c8 * 8);
    rBl[cc] = *(const u16x8*)(Wxtl + (size_t)(n_base + r) * 256 + c8 * 8);
  }

  for (int kb = 0; kb < 256; kb += 64) {
    // ---- write phase ----
#pragma unroll
    for (int cc = 0; cc < 2; cc++) {  // A: agg rows, split hi/lo
      int c = t + cc * 512;
      int r = c >> 4, c4 = c & 15;
      u16x4 hi, lo;
#pragma unroll
      for (int j = 0; j < 4; j++) {
        HiLo s = splitf(rA[cc][j]);
        hi[j] = s.hi; lo[j] = s.lo;
      }
      *(u16x4*)(Ah + swz64(r, c4 * 4)) = hi;
      *(u16x4*)(Al + swz64(r, c4 * 4)) = lo;
    }
#pragma unroll
    for (int cc = 0; cc < 2; cc++) {  // B: WxT copy
      int c = t + cc * 512;
      int r = c >> 3, c8 = c & 7;
      *(u16x8*)(Bh + swz64(r, c8 * 8)) = rBh[cc];
      *(u16x8*)(Bl + swz64(r, c8 * 8)) = rBl[cc];
    }
    __syncthreads();
    // ---- prefetch next K-tile (overlaps MFMA) ----
    if (kb + 64 < 256) {
      const int kn = kb + 64;
#pragma unroll
      for (int cc = 0; cc < 2; cc++) {
        int c = t + cc * 512;
        int r = c >> 4, c4 = c & 15;
        rA[cc] = *(const f32x4*)(agg + (size_t)(r0 + r) * 256 + kn + c4 * 4);
      }
#pragma unroll
      for (int cc = 0; cc < 2; cc++) {
        int c = t + cc * 512;
        int r = c >> 3, c8 = c & 7;
        rBh[cc] = *(const u16x8*)(Wxth + (size_t)(n_base + r) * 256 + kn + c8 * 8);
        rBl[cc] = *(const u16x8*)(Wxtl + (size_t)(n_base + r) * 256 + kn + c8 * 8);
      }
    }
    // ---- MFMA phase ----
#pragma unroll
    for (int kk = 0; kk < 64; kk += 32) {
      bf16x8 ah = __builtin_bit_cast(bf16x8, *(const u16x8*)(Ah + swz64(msub * 16 + l16, kk + quad * 8)));
      bf16x8 al = __builtin_bit_cast(bf16x8, *(const u16x8*)(Al + swz64(msub * 16 + l16, kk + quad * 8)));
#pragma unroll
      for (int tN = 0; tN < 4; tN++) {
        int brow = nsub * 64 + tN * 16 + l16;
        bf16x8 bh = __builtin_bit_cast(bf16x8, *(const u16x8*)(Bh + swz64(brow, kk + quad * 8)));
        bf16x8 bl = __builtin_bit_cast(bf16x8, *(const u16x8*)(Bl + swz64(brow, kk + quad * 8)));
        acc[tN] = __builtin_amdgcn_mfma_f32_16x16x32_bf16(ah, bh, acc[tN], 0, 0, 0);
        acc[tN] = __builtin_amdgcn_mfma_f32_16x16x32_bf16(ah, bl, acc[tN], 0, 0, 0);
        acc[tN] = __builtin_amdgcn_mfma_f32_16x16x32_bf16(al, bh, acc[tN], 0, 0, 0);
      }
    }
    __syncthreads();
  }
  const int rbase = r0 + msub * 16 + quad * 4;  // b*1024 + m
  const int bI = rbase >> 10;
#pragma unroll
  for (int tN = 0; tN < 4; tN++) {
    int u = n_base + nsub * 64 + tN * 16 + l16;
    float bu = bias[u];
#pragma unroll
    for (int i = 0; i < 4; i++) {
      int mI = (rbase + i) & 1023;
      Xpre[((size_t)mI * 8 + bI) * 256 + u] = acc[tN][i] + bu;
    }
  }
}

// ---------------- K4: sequential scan — R15 VERBATIM (623us proven) ---------
// 8 WGs (1 batch each), 8 waves. Wave w owns cols [w*32,w*32+32) = 2
// n-tiles. A-tile: 2 rows (h hi/lo), read row clamped to l16&1 ->
// broadcast, conflict-free. Quads 0/1 both hold valid (hi,lo) in C regs
// [0],[1]; quad0 -> tile0, quad1 -> tile1 -> 1 tanh chain/lane. MFMA
// interleave keeps 4 independent accumulator chains (a0a,a1a,a0b,a1b) —
// REQUIRED (R17: 2 chains exposed MFMA latency, +35%). All 8 ds_reads
// hoisted to step top. Nothing precedes MFMA issue (R16 lesson).
__global__ __launch_bounds__(512, 2) void rnn_scan(const u16* __restrict__ Whth,
                                                   const u16* __restrict__ Whtl,
                                                   const float* __restrict__ Xpre,
                                                   float* __restrict__ out) {
  __shared__ u16 h2[2][2 * HP_B];
  const int b = blockIdx.x;
  const int t = threadIdx.x;
  const int w = t >> 6, lane = t & 63, quad = lane >> 4, l16 = lane & 15;
  const int colbase = w * 32;
  const bool epi = (quad < 2);           // quad0 -> tile0, quad1 -> tile1
  const int col_e = colbase + quad * 16 + l16;  // valid for epi lanes

  // Preload Wh hi+lo fragments: 2 n-tiles x 8 k-blocks, hi+lo
  bf16x8 bwh[2][8], bwl[2][8];
#pragma unroll
  for (int tN = 0; tN < 2; tN++) {
    const u16* wph = Whth + (size_t)(colbase + tN * 16 + l16) * 256 + quad * 8;
    const u16* wpl = Whtl + (size_t)(colbase + tN * 16 + l16) * 256 + quad * 8;
#pragma unroll
    for (int kb = 0; kb < 8; kb++) {
      bwh[tN][kb] = __builtin_bit_cast(bf16x8, *(const u16x8*)(wph + kb * 32));
      bwl[tN][kb] = __builtin_bit_cast(bf16x8, *(const u16x8*)(wpl + kb * 32));
    }
  }
  for (int i = t; i < 2 * 2 * HP_B; i += 512) ((u16*)h2)[i] = 0;

  // c banks 0..3: additive input for steps m4+0..m4+3 (epi lanes only).
  float cb[4];
  if (epi) {
#pragma unroll
    for (int k = 0; k < 4; k++) cb[k] = Xpre[(size_t)k * 2048 + b * 256 + col_e];
  }
  // Running pointers (advance by constants; no per-step re-derivation).
  const float* ldp = Xpre + 4 * 2048 + b * 256 + col_e;
  float* outp = out + (size_t)b * 262144 + col_e;
  // Hoisted LDS bases. Read base: row clamped to l16&1 (broadcast dup rows).
  const u16* rb0 = &h2[0][(l16 & 1) * HP_B + quad * 8];
  const u16* rb1 = &h2[1][(l16 & 1) * HP_B + quad * 8];
  u16* wb0 = &h2[0][0];
  u16* wb1 = &h2[1][0];
  __syncthreads();

  for (int m4 = 0; m4 < 1024; m4 += 4) {
#pragma unroll
    for (int k = 0; k < 4; k++) {
      const int p = k & 1;                       // compile-time in unrolled body
      const u16* rb = p ? rb1 : rb0;
      u16* hw = p ? wb0 : wb1;                   // write the other buffer

      // Hoist all 8 A-fragment reads (one lgkmcnt ramp, MFMAs pipeline).
      bf16x8 af[8];
#pragma unroll
      for (int kb = 0; kb < 8; kb++)
        af[kb] = __builtin_bit_cast(bf16x8, *(const u16x8*)(rb + kb * 32));

      f32x4 a0a = {0.f,0.f,0.f,0.f}, a0b = {0.f,0.f,0.f,0.f};
      f32x4 a1a = {0.f,0.f,0.f,0.f}, a1b = {0.f,0.f,0.f,0.f};
#pragma unroll
      for (int kb = 0; kb < 4; kb++) {
        a0a = __builtin_amdgcn_mfma_f32_16x16x32_bf16(af[kb], bwh[0][kb], a0a, 0, 0, 0);
        a1a = __builtin_amdgcn_mfma_f32_16x16x32_bf16(af[kb], bwh[1][kb], a1a, 0, 0, 0);
        a0b = __builtin_amdgcn_mfma_f32_16x16x32_bf16(af[kb + 4], bwh[0][kb + 4], a0b, 0, 0, 0);
        a1b = __builtin_amdgcn_mfma_f32_16x16x32_bf16(af[kb + 4], bwh[1][kb + 4], a1b, 0, 0, 0);
        a0a = __builtin_amdgcn_mfma_f32_16x16x32_bf16(af[kb], bwl[0][kb], a0a, 0, 0, 0);
        a1a = __builtin_amdgcn_mfma_f32_16x16x32_bf16(af[kb], bwl[1][kb], a1a, 0, 0, 0);
        a0b = __builtin_amdgcn_mfma_f32_16x16x32_bf16(af[kb + 4], bwl[0][kb + 4], a0b, 0, 0, 0);
        a1b = __builtin_amdgcn_mfma_f32_16x16x32_bf16(af[kb + 4], bwl[1][kb + 4], a1b, 0, 0, 0);
      }

      // Epilogue distributed: quad0 uses (a0a,a0b), quad1 uses (a1a,a1b).
      if (epi) {
        float sA0 = quad ? a1a[0] : a0a[0];
        float sA1 = quad ? a1a[1] : a0a[1];
        float sB0 = quad ? a1b[0] : a0b[0];
        float sB1 = quad ? a1b[1] : a0b[1];
        float hi_part = sA0 + sB0;
        float lo_part = sA1 + sB1;
        float x = (hi_part + lo_part) + cb[k];
        float y = tanh_fast(x);
        HiLo s = splitf(y);
        hw[col_e] = s.hi;           // row 0 = h_hi
        hw[HP_B + col_e] = s.lo;    // row 1 = h_lo
        *outp = y;                  // fire-and-forget (vmcnt never drained)
        // Prefetch c for step m+4 into the bank just consumed.
        if (m4 <= 1019 - k) {
          cb[k] = *ldp;
          ldp += 2048;
        }
      }
      outp += 256;
      sync_lds_only();
    }
  }
}

extern "C" void kernel_launch(void* const* d_in, const int* in_sizes, int n_in,
                              void* d_out, int out_size, void* d_ws, size_t ws_size,
                              hipStream_t stream) {
  (void)in_sizes; (void)n_in; (void)out_size; (void)ws_size;
  const float* seq   = (const float*)d_in[0];  // (8,1024,256) f32
  const float* graph = (const float*)d_in[1];  // (8,1024,1024) f32
  const float* E     = (const float*)d_in[2];  // (256,256) f32
  const float* Wx    = (const float*)d_in[3];  // (256,256) f32
  const float* Wh    = (const float*)d_in[4];  // (256,256) f32
  const float* bias  = (const float*)d_in[5];  // (256,) f32
  float* out = (float*)d_out;                  // (8,1024,256) f32

  // workspace layout (bytes): ~26 MB total
  char* w = (char*)d_ws;
  float* rnorm  = (float*)(w + 0);          //  32 KB
  u16*   Wxth   = (u16*)(w + 294912);       // 128 KB each
  u16*   Wxtl   = (u16*)(w + 425984);
  u16*   Whth   = (u16*)(w + 557056);
  u16*   Whtl   = (u16*)(w + 688128);
  u16*   betaTh = (u16*)(w + 819200);       // 4 MB [b][u][l] (raw, no rnorm)
  u16*   betaTl = (u16*)(w + 5013504);      // 4 MB
  float* agg    = (float*)(w + 9207808);    // 8 MB [b][m][u]
  float* Xpre   = (float*)(w + 17596416);   // 8 MB [m][b][u]

  front1<<<1536, 512, 0, stream>>>(Wx, Wxth, Wxtl, Wh, Whth, Whtl,
                                   graph, rnorm, seq, E, betaTh, betaTl);
  gemm_agg<<<dim3(16, 2, 8), 512, 0, stream>>>(graph, betaTh, betaTl, rnorm, agg);
  gemm_xpre<<<dim3(128, 2), 512, 0, stream>>>(agg, Wxth, Wxtl, bias, Xpre);
  rnn_scan<<<dim3(8), 512, 0, stream>>>(Whth, Whtl, Xpre, out);
}